// Round 7
// baseline (30.694 us; speedup 1.0000x reference)
//
#include <hip/hip_runtime.h>
#include <math.h>

#define B_TOTAL 16384
#define NQ 512
#define NUM 3
#define WAVES_TOTAL 4096   // 1024 blocks * 4 waves; each wave owns 4 batches

// One wave per batch, 4 batches per wave, double-buffered register staging:
// loads for batch i+1 are issued before batch i is computed, so no wave ever
// stalls on its own pos loads. Compute is the R6-proven masked-argmax:
//   #1 = argmax conf; #2 = argmax among passers vs p1; #3 = passers vs p1&p2.
struct Stage {
    float4 c0, c1;                 // conf[8l..8l+7]
    float4 q0, q1, q2, q3, q4, q5; // pos rows 8l..8l+7 (96B contiguous)
};

__global__ __launch_bounds__(256) void greedy_nms_kernel(
    const float* __restrict__ conf,   // [B, NQ]
    const float* __restrict__ pos,    // [B, NQ, 3]
    float* __restrict__ out)          // [B, NUM, 3]
{
    const int lane = threadIdx.x & 63;
    const int wg   = (blockIdx.x << 2) | (threadIdx.x >> 6); // 0..4095

    auto issue = [&](int b, Stage& s) {
        const float4* cb4 = reinterpret_cast<const float4*>(conf + (size_t)b * NQ);
        s.c0 = cb4[lane * 2 + 0];
        s.c1 = cb4[lane * 2 + 1];
        const float4* pb4 = reinterpret_cast<const float4*>(pos + (size_t)b * NQ * 3);
        s.q0 = pb4[lane * 6 + 0];
        s.q1 = pb4[lane * 6 + 1];
        s.q2 = pb4[lane * 6 + 2];
        s.q3 = pb4[lane * 6 + 3];
        s.q4 = pb4[lane * 6 + 4];
        s.q5 = pb4[lane * 6 + 5];
    };

    const float TH  = 0.78539816339744830961f; // pi/4 (f32 == jnp thresh)
    const float CLO = 0.70710478f;             // cos(pi/4) - ~2e-6
    const float CHI = 0.70710878f;             // cos(pi/4) + ~2e-6

    auto process = [&](int b, const Stage& s) {
        // monotone float->u32 keys (no NaNs); key 0 == "consumed/failed"
        unsigned k[8];
        {
            float f[8] = {s.c0.x, s.c0.y, s.c0.z, s.c0.w,
                          s.c1.x, s.c1.y, s.c1.z, s.c1.w};
            #pragma unroll
            for (int i = 0; i < 8; ++i) {
                int bi = __float_as_int(f[i]);
                k[i] = (unsigned)bi ^ ((unsigned)(bi >> 31) | 0x80000000u);
            }
        }
        // unpack 8 pos rows (row j = element 8*lane + j)
        float rx[8], ry[8], rz[8];
        {
            float fl[24] = {s.q0.x, s.q0.y, s.q0.z, s.q0.w,
                            s.q1.x, s.q1.y, s.q1.z, s.q1.w,
                            s.q2.x, s.q2.y, s.q2.z, s.q2.w,
                            s.q3.x, s.q3.y, s.q3.z, s.q3.w,
                            s.q4.x, s.q4.y, s.q4.z, s.q4.w,
                            s.q5.x, s.q5.y, s.q5.z, s.q5.w};
            #pragma unroll
            for (int j = 0; j < 8; ++j) {
                rx[j] = fl[3 * j + 0];
                ry[j] = fl[3 * j + 1];
                rz[j] = fl[3 * j + 2];
            }
        }

        // exact argmax (min-index tie-break via ballot+ffs)
        auto argmax_idx = [&](unsigned& gm_out) -> int {
            unsigned m = k[0];
            #pragma unroll
            for (int i = 1; i < 8; ++i) m = k[i] > m ? k[i] : m;
            unsigned gm = m;
            #pragma unroll
            for (int off = 1; off < 64; off <<= 1) {
                unsigned o = __shfl_xor(gm, off);
                gm = o > gm ? o : gm;
            }
            int sl = 8;
            #pragma unroll
            for (int i = 7; i >= 0; --i)
                if (k[i] == gm) sl = i;
            unsigned long long ball = __ballot(sl < 8);
            int owner = __ffsll(ball) - 1;
            int osl = __shfl(sl, owner);
            gm_out = gm;
            return owner * 8 + osl;
        };

        auto get_row = [&](int w, float& x, float& y, float& z) {
            const int ow = w >> 3, sl = w & 7;
            float tx = rx[0], ty = ry[0], tz = rz[0];
            #pragma unroll
            for (int i = 1; i < 8; ++i)
                if (sl == i) { tx = rx[i]; ty = ry[i]; tz = rz[i]; }
            x = __shfl(tx, ow); y = __shfl(ty, ow); z = __shfl(tz, ow);
        };

        auto mask_keys = [&](float px, float py, float pz) {
            #pragma unroll
            for (int i = 0; i < 8; ++i) {
                float d = fabsf(rx[i] * px + ry[i] * py + rz[i] * pz);
                bool pass;
                if (d <= CLO)      pass = true;
                else if (d >= CHI) pass = false;
                else               pass = (acosf(fminf(d, 1.f)) >= TH);
                if (!pass) k[i] = 0u;
            }
        };

        // #1
        unsigned gm1;
        int w1 = argmax_idx(gm1);
        float p1x, p1y, p1z;
        get_row(w1, p1x, p1y, p1z);
        {
            const int osl = ((w1 >> 3) == lane) ? (w1 & 7) : 8;
            #pragma unroll
            for (int i = 0; i < 8; ++i)
                if (osl == i) k[i] = 0u;
        }

        float p0x, p0y, p0z;                 // fallback = pos[0]
        get_row(0, p0x, p0y, p0z);

        // #2
        mask_keys(p1x, p1y, p1z);
        unsigned gm2;
        int w2 = argmax_idx(gm2);

        float o2x = p0x, o2y = p0y, o2z = p0z;
        float o3x = p0x, o3y = p0y, o3z = p0z;
        if (gm2 != 0u) {                     // wave-uniform
            float p2x, p2y, p2z;
            get_row(w2, p2x, p2y, p2z);
            o2x = p2x; o2y = p2y; o2z = p2z;
            // #3 (w2 self-fails: |dot|=1)
            mask_keys(p2x, p2y, p2z);
            unsigned gm3;
            int w3 = argmax_idx(gm3);
            if (gm3 != 0u) get_row(w3, o3x, o3y, o3z);
        }

        if (lane == 0) {
            float* ob = out + (size_t)b * 9;
            ob[0] = p1x; ob[1] = p1y; ob[2] = p1z;
            ob[3] = o2x; ob[4] = o2y; ob[5] = o2z;
            ob[6] = o3x; ob[7] = o3y; ob[8] = o3z;
        }
    };

    // statically scheduled 4-batch pipeline, 1-deep register double-buffer
    const int b0 = wg;
    const int b1 = wg + WAVES_TOTAL;
    const int b2 = wg + 2 * WAVES_TOTAL;
    const int b3 = wg + 3 * WAVES_TOTAL;

    Stage A, Bst;
    issue(b0, A);
    issue(b1, Bst);
    process(b0, A);
    issue(b2, A);
    process(b1, Bst);
    issue(b3, Bst);
    process(b2, A);
    process(b3, Bst);
}

extern "C" void kernel_launch(void* const* d_in, const int* in_sizes, int n_in,
                              void* d_out, int out_size, void* d_ws, size_t ws_size,
                              hipStream_t stream) {
    const float* pred_logits = (const float*)d_in[0]; // [B, NQ, 1]
    const float* pred_pos    = (const float*)d_in[1]; // [B, NQ, 3]
    float* out = (float*)d_out;                       // [B, NUM, 3]

    greedy_nms_kernel<<<WAVES_TOTAL / 4, 256, 0, stream>>>(pred_logits, pred_pos, out);
}